// Round 1
// baseline (195.704 us; speedup 1.0000x reference)
//
#include <hip/hip_runtime.h>
#include <hip/hip_bf16.h>

// Problem constants
#define BSZ 16
#define CDIM 256
#define NPIX 1024
#define NH 4
#define DHD 64
#define EPSV 1e-6f
#define QSCALE 0.0625f   // 1/sqrt(DIM)
#define INV_SQRT2 0.70710678118654752440f

typedef __attribute__((ext_vector_type(4))) float f32x4;
typedef __attribute__((ext_vector_type(8))) __bf16 bf16x8;
typedef __attribute__((ext_vector_type(4))) __bf16 bf16x4;

// Workspace layout (bytes). Total = 49.5 MB.
#define OFF_WBF   0UL                          // 4 x 65536 bf16 = 512 KB
#define OFF_STATS (512UL*1024)                 // 2*16*32 float2 = 8 KB
#define OFF_ANT   (1024UL*1024)                // [b][p][c] bf16, 8 MB
#define OFF_BNT   (OFF_ANT + 8UL*1024*1024)
#define OFF_Q     (OFF_BNT + 8UL*1024*1024)    // [bh][p][d] bf16, 8 MB
#define OFF_K     (OFF_Q   + 8UL*1024*1024)    // [bh][p][d]
#define OFF_V     (OFF_K   + 8UL*1024*1024)    // [bh][d][p]
#define OFF_H     (OFF_V   + 8UL*1024*1024)    // [b][p][c]

// ---------------- weights -> bf16 (Wq pre-scaled by 1/sqrt(DIM)) -------------
__global__ __launch_bounds__(256) void prep_w(const float* __restrict__ Wq, const float* __restrict__ Wk,
                                              const float* __restrict__ Wv, const float* __restrict__ Wp,
                                              __bf16* __restrict__ out){
  int m = blockIdx.y;
  const float* src = (m==0)?Wq:(m==1)?Wk:(m==2)?Wv:Wp;
  float scale = (m==0)?QSCALE:1.0f;
  int idx = (blockIdx.x*256 + threadIdx.x)*4;
  float4 v = *(const float4*)(src + idx);
  bf16x4 o;
  o[0]=(__bf16)(v.x*scale); o[1]=(__bf16)(v.y*scale);
  o[2]=(__bf16)(v.z*scale); o[3]=(__bf16)(v.w*scale);
  *(bf16x4*)(out + m*65536 + idx) = o;
}

// ---------------- groupnorm stats: mean/rstd per (tensor, b, g) --------------
__global__ __launch_bounds__(256) void gn_stats(const float* __restrict__ xa, const float* __restrict__ xb,
                                                float2* __restrict__ stats){
  int bx = blockIdx.x;              // 0..1023 = t(2) * b(16) * g(32)
  int t = bx >> 9; int rem = bx & 511; int bb = rem >> 5; int g = rem & 31;
  const float* src = (t ? xb : xa) + ((size_t)(bb*CDIM + g*8))*NPIX;
  float s = 0.f, ss = 0.f;
  for (int i = 0; i < 8; i++){
    float4 v = *(const float4*)(src + (threadIdx.x + 256*i)*4);
    s  += v.x+v.y+v.z+v.w;
    ss += v.x*v.x+v.y*v.y+v.z*v.z+v.w*v.w;
  }
  __shared__ float rs[256], rss[256];
  rs[threadIdx.x]=s; rss[threadIdx.x]=ss; __syncthreads();
  for (int st=128; st>0; st>>=1){
    if (threadIdx.x < st){ rs[threadIdx.x]+=rs[threadIdx.x+st]; rss[threadIdx.x]+=rss[threadIdx.x+st]; }
    __syncthreads();
  }
  if (threadIdx.x==0){
    float mean = rs[0]*(1.0f/8192.0f);
    float var  = rss[0]*(1.0f/8192.0f) - mean*mean;
    stats[(t*16+bb)*32+g] = make_float2(mean, rsqrtf(var + EPSV));
  }
}

// ------------- normalize + transpose to [b][p][c] bf16 -----------------------
__global__ __launch_bounds__(256) void norm_t(const float* __restrict__ xa, const float* __restrict__ xb,
                                              const float* __restrict__ gAw, const float* __restrict__ gAb,
                                              const float* __restrict__ gBw, const float* __restrict__ gBb,
                                              const float2* __restrict__ stats,
                                              __bf16* __restrict__ ant, __bf16* __restrict__ bnt){
  __shared__ __align__(16) __bf16 T[64][72];
  int t = blockIdx.z;
  const float* src = t ? xb : xa;
  const float* gw  = t ? gBw : gAw;
  const float* gb  = t ? gBb : gAb;
  __bf16* dst = t ? bnt : ant;
  int bb = blockIdx.y >> 2, cblk = blockIdx.y & 3;
  int p0 = blockIdx.x*64, c0 = cblk*64;
  int tid = threadIdx.x;
  int r16 = tid>>4, c4 = tid&15;
  for (int pass=0; pass<4; pass++){
    int cl = r16 + 16*pass;
    int c  = c0 + cl;
    float2 ms = stats[(t*16+bb)*32 + (c>>3)];
    float sc  = ms.y * gw[c];
    float off = gb[c] - ms.x*sc;
    float4 v = *(const float4*)(src + ((size_t)(bb*CDIM + c))*NPIX + p0 + c4*4);
    T[c4*4+0][cl] = (__bf16)(v.x*sc+off);
    T[c4*4+1][cl] = (__bf16)(v.y*sc+off);
    T[c4*4+2][cl] = (__bf16)(v.z*sc+off);
    T[c4*4+3][cl] = (__bf16)(v.w*sc+off);
  }
  __syncthreads();
  for (int pass=0; pass<2; pass++){
    int slot = tid + 256*pass;
    int pl = slot>>3, ch = slot&7;
    *(float4*)(dst + ((size_t)(bb*NPIX + p0 + pl))*CDIM + c0 + ch*8) = *(float4*)&T[pl][ch*8];
  }
}

// ------------- generic 64x64x256 bf16 MFMA GEMM, D[m][n] = sum_k A[m][k]B'[n][k]
// mode 0: Q/K  (m=o 4-consec d, n=bp)   -> dst [bh][p][d] bf16, bias*bias_scale
// mode 2: V    (m=bp 4-consec p, n=o)   -> dst [bh][d][p] bf16, +bias
// mode 3: OUT  (m=bp 4-consec p, n=o)   -> dst fp32 [b][o][p], (skip+acc+bias)*inv_sqrt2
__global__ __launch_bounds__(256) void gemm_k(const __bf16* __restrict__ A, const __bf16* __restrict__ Bm,
                                              const float* __restrict__ bias, float bias_scale,
                                              void* __restrict__ dst_, const float* __restrict__ skip,
                                              int mode){
  __shared__ __align__(16) __bf16 As[64][72], Bs[64][72];
  int tid = threadIdx.x;
  int m0 = blockIdx.y*64, n0 = blockIdx.x*64;
  int lane = tid & 63, wid = tid >> 6;
  int wm = (wid>>1)*32, wn = (wid&1)*32;
  int g = lane>>4, c = lane&15;
  f32x4 acc[2][2];
  #pragma unroll
  for (int i=0;i<2;i++)
    #pragma unroll
    for (int j=0;j<2;j++) acc[i][j] = (f32x4){0.f,0.f,0.f,0.f};

  for (int k0=0; k0<256; k0+=64){
    #pragma unroll
    for (int i=0;i<2;i++){
      int slot = tid + 256*i;
      int row = slot>>3, ch = slot&7;
      *(float4*)&As[row][ch*8] = *(const float4*)(A  + (size_t)(m0+row)*256 + k0 + ch*8);
      *(float4*)&Bs[row][ch*8] = *(const float4*)(Bm + (size_t)(n0+row)*256 + k0 + ch*8);
    }
    __syncthreads();
    #pragma unroll
    for (int ks=0; ks<2; ks++){
      bf16x8 af0 = *(bf16x8*)&As[wm +      c][ks*32 + g*8];
      bf16x8 af1 = *(bf16x8*)&As[wm + 16 + c][ks*32 + g*8];
      bf16x8 bf0 = *(bf16x8*)&Bs[wn +      c][ks*32 + g*8];
      bf16x8 bf1 = *(bf16x8*)&Bs[wn + 16 + c][ks*32 + g*8];
      acc[0][0] = __builtin_amdgcn_mfma_f32_16x16x32_bf16(af0, bf0, acc[0][0], 0,0,0);
      acc[0][1] = __builtin_amdgcn_mfma_f32_16x16x32_bf16(af0, bf1, acc[0][1], 0,0,0);
      acc[1][0] = __builtin_amdgcn_mfma_f32_16x16x32_bf16(af1, bf0, acc[1][0], 0,0,0);
      acc[1][1] = __builtin_amdgcn_mfma_f32_16x16x32_bf16(af1, bf1, acc[1][1], 0,0,0);
    }
    __syncthreads();
  }

  #pragma unroll
  for (int fm=0; fm<2; fm++){
    #pragma unroll
    for (int fn=0; fn<2; fn++){
      int m = m0 + wm + fm*16 + g*4;   // rows m..m+3
      int n = n0 + wn + fn*16 + c;
      f32x4 v = acc[fm][fn];
      if (mode <= 1){
        // m = o (4 consecutive d), n = b*1024+p
        int bb = n>>10, p = n&1023;
        int o = m, h = o>>6, d = o&63;
        bf16x4 pk;
        #pragma unroll
        for (int r=0;r<4;r++) pk[r] = (__bf16)(v[r] + bias[o+r]*bias_scale);
        *(bf16x4*)((__bf16*)dst_ + ((size_t)((bb*4+h)*1024 + p))*64 + d) = pk;
      } else if (mode == 2){
        // m = b*1024+p (4 consecutive p), n = o
        int bb = m>>10, p = m&1023;
        int o = n, h = o>>6, d = o&63;
        float bv = bias[o];
        bf16x4 pk;
        #pragma unroll
        for (int r=0;r<4;r++) pk[r] = (__bf16)(v[r] + bv);
        *(bf16x4*)((__bf16*)dst_ + ((size_t)((bb*4+h)*64 + d))*1024 + p) = pk;
      } else {
        int bb = m>>10, p = m&1023;
        int o = n;
        float bv = bias[o];
        size_t addr = (size_t)(bb*256 + o)*1024 + p;
        float4 sk = *(const float4*)(skip + addr);
        float4 ov;
        ov.x = (sk.x + v[0] + bv)*INV_SQRT2;
        ov.y = (sk.y + v[1] + bv)*INV_SQRT2;
        ov.z = (sk.z + v[2] + bv)*INV_SQRT2;
        ov.w = (sk.w + v[3] + bv)*INV_SQRT2;
        *(float4*)((float*)dst_ + addr) = ov;
      }
    }
  }
}

// ------------- attention: per (b,h), 64-query block, exp-no-max softmax ------
__global__ __launch_bounds__(256) void attn_k(const __bf16* __restrict__ q, const __bf16* __restrict__ k,
                                              const __bf16* __restrict__ v, __bf16* __restrict__ hout){
  __shared__ __align__(16) __bf16 Kl[64][72], Vl[64][72], Pl[4][16][72];
  __shared__ float l_lds[4][16];
  int bh = blockIdx.y;               // b*4+h
  int qblk = blockIdx.x;             // 0..15
  int tid = threadIdx.x, lane = tid&63, w = tid>>6;
  int g = lane>>4, c = lane&15;
  int bb = bh>>2, h = bh&3;
  const __bf16* qbase = q + (size_t)bh*NPIX*DHD;
  const __bf16* kbase = k + (size_t)bh*NPIX*DHD;
  const __bf16* vbase = v + (size_t)bh*DHD*NPIX;

  int qrow = qblk*64 + w*16 + c;
  bf16x8 qf0 = *(const bf16x8*)(qbase + (size_t)qrow*64 +      g*8);
  bf16x8 qf1 = *(const bf16x8*)(qbase + (size_t)qrow*64 + 32 + g*8);

  f32x4 oacc[4];
  #pragma unroll
  for (int i=0;i<4;i++) oacc[i] = (f32x4){0.f,0.f,0.f,0.f};
  float l0=0.f, l1=0.f, l2=0.f, l3=0.f;

  for (int kt=0; kt<16; kt++){
    #pragma unroll
    for (int i=0;i<2;i++){
      int slot = tid + 256*i;
      int row = slot>>3, ch = slot&7;
      *(float4*)&Kl[row][ch*8] = *(const float4*)(kbase + (size_t)(kt*64+row)*64 + ch*8);
      *(float4*)&Vl[row][ch*8] = *(const float4*)(vbase + (size_t)row*1024 + kt*64 + ch*8);
    }
    __syncthreads();
    // scores S[q][pk] for this wave's 16 queries x 64 keys
    f32x4 s[4];
    #pragma unroll
    for (int fn=0; fn<4; fn++){
      bf16x8 kb0 = *(bf16x8*)&Kl[fn*16 + c][     g*8];
      bf16x8 kb1 = *(bf16x8*)&Kl[fn*16 + c][32 + g*8];
      f32x4 z = (f32x4){0.f,0.f,0.f,0.f};
      z     = __builtin_amdgcn_mfma_f32_16x16x32_bf16(qf0, kb0, z, 0,0,0);
      s[fn] = __builtin_amdgcn_mfma_f32_16x16x32_bf16(qf1, kb1, z, 0,0,0);
    }
    // P = exp(S)  (scores bounded ~|3.5|, no max subtraction needed)
    #pragma unroll
    for (int fn=0; fn<4; fn++){
      float p0 = __expf(s[fn][0]); l0 += p0; Pl[w][g*4+0][fn*16+c] = (__bf16)p0;
      float p1 = __expf(s[fn][1]); l1 += p1; Pl[w][g*4+1][fn*16+c] = (__bf16)p1;
      float p2 = __expf(s[fn][2]); l2 += p2; Pl[w][g*4+2][fn*16+c] = (__bf16)p2;
      float p3 = __expf(s[fn][3]); l3 += p3; Pl[w][g*4+3][fn*16+c] = (__bf16)p3;
    }
    // h^T += V^T * P^T
    bf16x8 pb0 = *(bf16x8*)&Pl[w][c][     g*8];
    bf16x8 pb1 = *(bf16x8*)&Pl[w][c][32 + g*8];
    #pragma unroll
    for (int fm=0; fm<4; fm++){
      bf16x8 va0 = *(bf16x8*)&Vl[fm*16+c][     g*8];
      bf16x8 va1 = *(bf16x8*)&Vl[fm*16+c][32 + g*8];
      oacc[fm] = __builtin_amdgcn_mfma_f32_16x16x32_bf16(va0, pb0, oacc[fm], 0,0,0);
      oacc[fm] = __builtin_amdgcn_mfma_f32_16x16x32_bf16(va1, pb1, oacc[fm], 0,0,0);
    }
    __syncthreads();
  }

  // reduce l across the 16 column-lanes (masks flip low 4 bits only)
  l0 += __shfl_xor(l0,1); l0 += __shfl_xor(l0,2); l0 += __shfl_xor(l0,4); l0 += __shfl_xor(l0,8);
  l1 += __shfl_xor(l1,1); l1 += __shfl_xor(l1,2); l1 += __shfl_xor(l1,4); l1 += __shfl_xor(l1,8);
  l2 += __shfl_xor(l2,1); l2 += __shfl_xor(l2,2); l2 += __shfl_xor(l2,4); l2 += __shfl_xor(l2,8);
  l3 += __shfl_xor(l3,1); l3 += __shfl_xor(l3,2); l3 += __shfl_xor(l3,4); l3 += __shfl_xor(l3,8);
  float lv = (c==0)?l0:(c==1)?l1:(c==2)?l2:l3;
  if (c < 4) l_lds[w][g*4+c] = lv;
  __syncthreads();
  float linv = 1.0f / l_lds[w][c];

  int qg = qblk*64 + w*16 + c;   // this lane's query (O^T column)
  #pragma unroll
  for (int fm=0; fm<4; fm++){
    bf16x4 pk;
    #pragma unroll
    for (int r=0;r<4;r++) pk[r] = (__bf16)(oacc[fm][r]*linv);
    *(bf16x4*)(hout + ((size_t)(bb*NPIX + qg))*CDIM + h*64 + fm*16 + g*4) = pk;
  }
}

extern "C" void kernel_launch(void* const* d_in, const int* in_sizes, int n_in,
                              void* d_out, int out_size, void* d_ws, size_t ws_size,
                              hipStream_t stream) {
  const float* xa  = (const float*)d_in[0];
  const float* xb  = (const float*)d_in[1];
  const float* Wq  = (const float*)d_in[2];
  const float* bq  = (const float*)d_in[3];
  const float* Wk  = (const float*)d_in[4];
  const float* bk  = (const float*)d_in[5];
  const float* Wv  = (const float*)d_in[6];
  const float* bv  = (const float*)d_in[7];
  const float* Wp  = (const float*)d_in[8];
  const float* bp  = (const float*)d_in[9];
  const float* gAw = (const float*)d_in[10];
  const float* gAb = (const float*)d_in[11];
  const float* gBw = (const float*)d_in[12];
  const float* gBb = (const float*)d_in[13];

  char* ws = (char*)d_ws;
  __bf16* wbf   = (__bf16*)(ws + OFF_WBF);
  float2* stats = (float2*)(ws + OFF_STATS);
  __bf16* ant   = (__bf16*)(ws + OFF_ANT);
  __bf16* bnt   = (__bf16*)(ws + OFF_BNT);
  __bf16* qws   = (__bf16*)(ws + OFF_Q);
  __bf16* kws   = (__bf16*)(ws + OFF_K);
  __bf16* vws   = (__bf16*)(ws + OFF_V);
  __bf16* hws   = (__bf16*)(ws + OFF_H);

  prep_w<<<dim3(64,4), 256, 0, stream>>>(Wq, Wk, Wv, Wp, wbf);
  gn_stats<<<1024, 256, 0, stream>>>(xa, xb, stats);
  norm_t<<<dim3(16,64,2), 256, 0, stream>>>(xa, xb, gAw, gAb, gBw, gBb, stats, ant, bnt);
  // Q = (Wq/16) * bn + bq/16   (stored [bh][p][d])
  gemm_k<<<dim3(256,4), 256, 0, stream>>>(wbf,           bnt, bq, QSCALE, qws, nullptr, 0);
  // K = Wk * an + bk           (stored [bh][p][d])
  gemm_k<<<dim3(256,4), 256, 0, stream>>>(wbf + 65536,   ant, bk, 1.0f,   kws, nullptr, 0);
  // V = Wv * an + bv           (stored [bh][d][p])
  gemm_k<<<dim3(4,256), 256, 0, stream>>>(ant, wbf + 2*65536, bv, 1.0f,   vws, nullptr, 2);
  attn_k<<<dim3(16,64), 256, 0, stream>>>(qws, kws, vws, hws);
  // out = (b + Wp*h + bp)/sqrt(2)
  gemm_k<<<dim3(4,256), 256, 0, stream>>>(hws, wbf + 3*65536, bp, 1.0f, d_out, xb, 3);
}